// Round 6
// baseline (336.619 us; speedup 1.0000x reference)
//
#include <hip/hip_runtime.h>
#include <hip/hip_bf16.h>
#include <cstdint>

#define NN 50000
#define NE 800000
#define DIM 256
#define NH 8
#define NB 196          // (NN+255)/256

typedef short v8s __attribute__((ext_vector_type(8)));
typedef float v4f __attribute__((ext_vector_type(4)));
typedef unsigned short u16x8 __attribute__((ext_vector_type(8)));

__device__ __forceinline__ float b2f(unsigned short u) {
    union { float f; uint32_t i; } c; c.i = ((uint32_t)u) << 16; return c.f;
}
__device__ __forceinline__ unsigned short f2b(float f) {
    union { float f; uint32_t i; } c; c.f = f;
    uint32_t lsb = (c.i >> 16) & 1u;
    return (unsigned short)((c.i + 0x7FFFu + lsb) >> 16);
}

// ---------------------------------------------------------- degree histogram
// int64 vs int32 layout probe: odd words of the first 64 entries are int64
// high halves (all zero) or int32 values (never all zero for random data).
__global__ __launch_bounds__(256) void deg_kernel(const int* __restrict__ e,
                                                  int* __restrict__ deg) {
    const int i = blockIdx.x * 256 + threadIdx.x;   // NE = 3125*256 exactly
    const int lane = threadIdx.x & 63;
    int probe = e[2 * lane + 1];
    unsigned long long nz = __ballot(probe != 0);
    bool is64 = (nz == 0ull);
    int d = is64 ? e[2 * (NE + i)] : e[NE + i];
    atomicAdd(&deg[d], 1);
}

// ------------------------------------------------------------- W -> Wt bf16
__global__ __launch_bounds__(256) void cvtw_kernel(const float* __restrict__ W,
                                                   unsigned short* __restrict__ Wt) {
    int idx = blockIdx.x * 256 + threadIdx.x;   // grid 256 -> 65536
    int k = idx >> 8, n = idx & 255;
    Wt[n * DIM + k] = f2b(W[k * DIM + n]);
}

// ------------------------------------- GEMM h = x@W  (+ fused attention dots)
// BM=128 x BN=256 (full width), 512 threads (8 waves: 2 wr x 4 wc), BK=64.
// Epilogue computes a_src[n][h], a_dst[n][h] from the f32 accumulators:
// cols of fragment (wc,j) all belong to head = 2*wc + (j>>1).
#define LDA3 72
__global__ __launch_bounds__(512) void gemm_kernel(
    const float* __restrict__ X, const unsigned short* __restrict__ Wt,
    const float* __restrict__ ASRC, const float* __restrict__ ADST,
    unsigned short* __restrict__ H, float* __restrict__ a_srcG,
    float* __restrict__ a_dstG) {
    __shared__ __align__(16) unsigned short As[128 * LDA3];
    __shared__ __align__(16) unsigned short Bs[256 * LDA3];
    const int t = threadIdx.x;
    const int wave = t >> 6, lane = t & 63;
    const int wr = wave >> 2, wc = wave & 3;
    const int fr = lane & 15, fq = lane >> 4;
    const int m0 = blockIdx.x * 128;

    v4f acc[4][4];
    #pragma unroll
    for (int mi = 0; mi < 4; ++mi)
        #pragma unroll
        for (int j = 0; j < 4; ++j) acc[mi][j] = (v4f){0.f, 0.f, 0.f, 0.f};

    #pragma unroll
    for (int kt = 0; kt < 256; kt += 64) {
        // stage A: 128 rows x 64 f32 -> bf16 (2048 float4, 4/thread)
        #pragma unroll
        for (int it = 0; it < 4; ++it) {
            int v = t + it * 512;
            int row = v >> 4;
            int c4 = (v & 15) << 2;
            int gr = m0 + row;
            float4 val = make_float4(0.f, 0.f, 0.f, 0.f);
            if (gr < NN) val = *(const float4*)(X + (size_t)gr * DIM + kt + c4);
            ushort4 o;
            o.x = f2b(val.x); o.y = f2b(val.y); o.z = f2b(val.z); o.w = f2b(val.w);
            *(ushort4*)(As + row * LDA3 + c4) = o;
        }
        // stage B: 256 rows x 64 shorts (2048 vec8, 4/thread)
        #pragma unroll
        for (int it = 0; it < 4; ++it) {
            int v = t + it * 512;
            int row = v >> 3;
            int kv = (v & 7) << 3;
            u16x8 val = *(const u16x8*)(Wt + (size_t)row * DIM + kt + kv);
            *(u16x8*)(Bs + row * LDA3 + kv) = val;
        }
        __syncthreads();
        #pragma unroll
        for (int ks = 0; ks < 64; ks += 32) {
            v8s a[4];
            #pragma unroll
            for (int mi = 0; mi < 4; ++mi)
                a[mi] = *(const v8s*)(As + (wr * 64 + mi * 16 + fr) * LDA3 + ks + fq * 8);
            #pragma unroll
            for (int j = 0; j < 4; ++j) {
                v8s b = *(const v8s*)(Bs + (wc * 64 + j * 16 + fr) * LDA3 + ks + fq * 8);
                #pragma unroll
                for (int mi = 0; mi < 4; ++mi)
                    acc[mi][j] = __builtin_amdgcn_mfma_f32_16x16x32_bf16(a[mi], b, acc[mi][j], 0, 0, 0);
            }
        }
        __syncthreads();
    }

    // --- fused attention-logit epilogue ---
    // col(j) = wc*64 + j*16 + fr; head(j) = 2*wc + (j>>1); c_in_head = (j&1)*16 + fr
    float asv[4], adv[4];
    #pragma unroll
    for (int j = 0; j < 4; ++j) {
        int hidx = 2 * wc + (j >> 1);
        int cidx = ((j & 1) << 4) + fr;
        asv[j] = ASRC[hidx * 32 + cidx];
        adv[j] = ADST[hidx * 32 + cidx];
    }
    #pragma unroll
    for (int mi = 0; mi < 4; ++mi) {
        float tSA[4], tSB[4], tDA[4], tDB[4];
        #pragma unroll
        for (int r = 0; r < 4; ++r) {
            tSA[r] = acc[mi][0][r] * asv[0] + acc[mi][1][r] * asv[1];
            tSB[r] = acc[mi][2][r] * asv[2] + acc[mi][3][r] * asv[3];
            tDA[r] = acc[mi][0][r] * adv[0] + acc[mi][1][r] * adv[1];
            tDB[r] = acc[mi][2][r] * adv[2] + acc[mi][3][r] * adv[3];
            #pragma unroll
            for (int off = 1; off <= 8; off <<= 1) {
                tSA[r] += __shfl_xor(tSA[r], off);
                tSB[r] += __shfl_xor(tSB[r], off);
                tDA[r] += __shfl_xor(tDA[r], off);
                tDB[r] += __shfl_xor(tDB[r], off);
            }
        }
        if (fr == 0) {
            #pragma unroll
            for (int r = 0; r < 4; ++r) {
                int gr = m0 + wr * 64 + mi * 16 + fq * 4 + r;
                if (gr < NN) {
                    a_srcG[gr * NH + 2 * wc]     = tSA[r];
                    a_srcG[gr * NH + 2 * wc + 1] = tSB[r];
                    a_dstG[gr * NH + 2 * wc]     = tDA[r];
                    a_dstG[gr * NH + 2 * wc + 1] = tDB[r];
                }
            }
        }
    }

    // --- H write ---
    #pragma unroll
    for (int mi = 0; mi < 4; ++mi)
        #pragma unroll
        for (int j = 0; j < 4; ++j)
            #pragma unroll
            for (int r = 0; r < 4; ++r) {
                int gr = m0 + wr * 64 + mi * 16 + fq * 4 + r;
                int gc = wc * 64 + j * 16 + fr;
                if (gr < NN) H[(size_t)gr * DIM + gc] = f2b(acc[mi][j][r]);
            }
}

// ------------------------------------------------------------- two-level scan
__global__ __launch_bounds__(256) void scan1_kernel(const int* __restrict__ deg,
                                                    int* __restrict__ row_start,
                                                    int* __restrict__ bsum) {
    const int t = threadIdx.x, b = blockIdx.x;
    const int i = b * 256 + t;
    const int lane = t & 63, wave = t >> 6;
    int v = (i < NN) ? deg[i] : 0;
    int x = v;
    #pragma unroll
    for (int off = 1; off <= 32; off <<= 1) {
        int y = __shfl_up(x, off);
        if (lane >= off) x += y;
    }
    __shared__ int wt[4];
    if (lane == 63) wt[wave] = x;
    __syncthreads();
    int add = 0;
    #pragma unroll
    for (int w2 = 0; w2 < 4; ++w2) if (w2 < wave) add += wt[w2];
    int incl = x + add;
    if (i < NN) row_start[i] = incl - v;
    if (t == 255) bsum[b] = incl;
}

__global__ __launch_bounds__(256) void scan2_kernel(const int* __restrict__ bsum,
                                                    int* __restrict__ boff,
                                                    int* __restrict__ row_start) {
    const int t = threadIdx.x;
    const int lane = t & 63, wave = t >> 6;
    int v = (t < NB) ? bsum[t] : 0;
    int x = v;
    #pragma unroll
    for (int off = 1; off <= 32; off <<= 1) {
        int y = __shfl_up(x, off);
        if (lane >= off) x += y;
    }
    __shared__ int wt[4];
    if (lane == 63) wt[wave] = x;
    __syncthreads();
    int add = 0;
    #pragma unroll
    for (int w2 = 0; w2 < 4; ++w2) if (w2 < wave) add += wt[w2];
    int incl = x + add;
    if (t < NB) boff[t] = incl - v;
    if (t == 255) row_start[NN] = incl;
}

__global__ __launch_bounds__(256) void scan3_kernel(int* __restrict__ row_start,
                                                    const int* __restrict__ boff,
                                                    int* __restrict__ cursor) {
    const int i = blockIdx.x * 256 + threadIdx.x;
    if (i < NN) {
        int r = row_start[i] + boff[blockIdx.x];
        row_start[i] = r;
        cursor[i] = r;
    }
}

// -------------------------------------- CSR fill + per-edge softmax weights
// one thread per edge: scatter src into CSR slot and precompute all 8
// per-head exp(leaky(a_src+a_dst)) weights (edge-parallel, latency-hidden).
__global__ __launch_bounds__(256) void fill_kernel(
    const int* __restrict__ e, const float* __restrict__ a_src,
    const float* __restrict__ a_dst, int* __restrict__ cursor,
    int* __restrict__ csr_src, float* __restrict__ wcsr) {
    const int i = blockIdx.x * 256 + threadIdx.x;
    const int lane = threadIdx.x & 63;
    int probe = e[2 * lane + 1];
    unsigned long long nz = __ballot(probe != 0);
    bool is64 = (nz == 0ull);
    int s, d;
    if (is64) { s = e[2 * i]; d = e[2 * (NE + i)]; }
    else      { s = e[i];     d = e[NE + i]; }
    int pos = atomicAdd(&cursor[d], 1);
    csr_src[pos] = s;
    float4 as0 = *(const float4*)(a_src + (size_t)s * NH);
    float4 as1 = *(const float4*)(a_src + (size_t)s * NH + 4);
    float4 ad0 = *(const float4*)(a_dst + (size_t)d * NH);
    float4 ad1 = *(const float4*)(a_dst + (size_t)d * NH + 4);
    const float* asp0 = (const float*)&as0; const float* asp1 = (const float*)&as1;
    const float* adp0 = (const float*)&ad0; const float* adp1 = (const float*)&ad1;
    float4 w0, w1;
    float* wp0 = (float*)&w0; float* wp1 = (float*)&w1;
    #pragma unroll
    for (int h = 0; h < 4; ++h) {
        float lg = asp0[h] + adp0[h];
        lg = lg > 0.f ? lg : 0.2f * lg;
        wp0[h] = __expf(lg);
        float lg2 = asp1[h] + adp1[h];
        lg2 = lg2 > 0.f ? lg2 : 0.2f * lg2;
        wp1[h] = __expf(lg2);
    }
    *(float4*)(wcsr + (size_t)pos * NH) = w0;
    *(float4*)(wcsr + (size_t)pos * NH + 4) = w1;
}

// --------------------------------------- fused aggregate+ELU+LayerNorm
// one wave per dst node; slot=lane>>5 takes 4 contiguous edges of each
// 8-edge chunk; q=lane&31 owns channels q*8..q*8+7 (one 16B bf16 load/edge).
// weights pre-computed by fill -> inner loop is pure load+fma.
__global__ __launch_bounds__(256) void agg_kernel(
    const unsigned short* __restrict__ H, const int* __restrict__ row_start,
    const int* __restrict__ csr_src, const float* __restrict__ wcsr,
    const float* __restrict__ X, const float* __restrict__ BIAS,
    const float* __restrict__ LNS, const float* __restrict__ LNB,
    float* __restrict__ OUT) {
    const int wave = threadIdx.x >> 6, lane = threadIdx.x & 63;
    const int d = blockIdx.x * 4 + wave;
    if (d >= NN) return;
    const int base = row_start[d];
    const int degree = row_start[d + 1] - base;
    const int slot = lane >> 5;
    const int q = lane & 31;
    const int headq = q >> 2;

    // hoist epilogue operands
    float4 x0 = *(const float4*)(X + (size_t)d * DIM + q * 8);
    float4 x1 = *(const float4*)(X + (size_t)d * DIM + q * 8 + 4);
    float4 b0 = *(const float4*)(BIAS + q * 8);
    float4 b1 = *(const float4*)(BIAS + q * 8 + 4);
    float4 sc0 = *(const float4*)(LNS + q * 8);
    float4 sc1 = *(const float4*)(LNS + q * 8 + 4);
    float4 lb0 = *(const float4*)(LNB + q * 8);
    float4 lb1 = *(const float4*)(LNB + q * 8 + 4);

    float acc[8];
    #pragma unroll
    for (int j = 0; j < 8; ++j) acc[j] = 0.f;
    float sumw = 0.f;

    for (int c0 = 0; c0 < degree; c0 += 8) {
        const int e0 = c0 + slot * 4;
        const int rem = degree - e0;
        const size_t eb = (size_t)base + e0;
        int s0 = 0, s1 = 0, s2 = 0, s3 = 0;
        float w0 = 0.f, w1 = 0.f, w2 = 0.f, w3 = 0.f;
        if (rem > 0) { s0 = csr_src[eb];     w0 = wcsr[eb * NH + headq]; }
        if (rem > 1) { s1 = csr_src[eb + 1]; w1 = wcsr[(eb + 1) * NH + headq]; }
        if (rem > 2) { s2 = csr_src[eb + 2]; w2 = wcsr[(eb + 2) * NH + headq]; }
        if (rem > 3) { s3 = csr_src[eb + 3]; w3 = wcsr[(eb + 3) * NH + headq]; }
        u16x8 hv0 = *(const u16x8*)(H + (size_t)s0 * DIM + q * 8);
        u16x8 hv1 = *(const u16x8*)(H + (size_t)s1 * DIM + q * 8);
        u16x8 hv2 = *(const u16x8*)(H + (size_t)s2 * DIM + q * 8);
        u16x8 hv3 = *(const u16x8*)(H + (size_t)s3 * DIM + q * 8);
        sumw += (w0 + w1) + (w2 + w3);
        #pragma unroll
        for (int j = 0; j < 8; ++j) acc[j] += w0 * b2f(hv0[j]);
        #pragma unroll
        for (int j = 0; j < 8; ++j) acc[j] += w1 * b2f(hv1[j]);
        #pragma unroll
        for (int j = 0; j < 8; ++j) acc[j] += w2 * b2f(hv2[j]);
        #pragma unroll
        for (int j = 0; j < 8; ++j) acc[j] += w3 * b2f(hv3[j]);
    }

    // combine the two slots
    float sum_ex = sumw + __shfl_xor(sumw, 32);
    #pragma unroll
    for (int j = 0; j < 8; ++j) acc[j] += __shfl_xor(acc[j], 32);

    const float inv = 1.0f / (sum_ex + 1e-16f);

    const float* xp0 = (const float*)&x0; const float* xp1 = (const float*)&x1;
    const float* bp0 = (const float*)&b0; const float* bp1 = (const float*)&b1;
    float v[8];
    float s1v = 0.f, s2v = 0.f;
    #pragma unroll
    for (int j = 0; j < 8; ++j) {
        float xv = (j < 4) ? xp0[j] : xp1[j - 4];
        float bv = (j < 4) ? bp0[j] : bp1[j - 4];
        float t = acc[j] * inv + bv + xv;
        t = t > 0.f ? t : expm1f(t);   // ELU
        v[j] = t;
        s1v += t;
        s2v += t * t;
    }
    #pragma unroll
    for (int off = 16; off >= 1; off >>= 1) {
        s1v += __shfl_xor(s1v, off);
        s2v += __shfl_xor(s2v, off);
    }
    const float mean = s1v * (1.0f / 256.0f);
    float var = s2v * (1.0f / 256.0f) - mean * mean;
    var = fmaxf(var, 0.f);
    const float rstd = rsqrtf(var + 1e-5f);

    if (slot == 0) {
        const float* scp0 = (const float*)&sc0; const float* scp1 = (const float*)&sc1;
        const float* lbp0 = (const float*)&lb0; const float* lbp1 = (const float*)&lb1;
        float4 o0, o1;
        float* op0 = (float*)&o0; float* op1 = (float*)&o1;
        #pragma unroll
        for (int j = 0; j < 4; ++j) {
            op0[j] = (v[j] - mean) * rstd * scp0[j] + lbp0[j];
            op1[j] = (v[j + 4] - mean) * rstd * scp1[j] + lbp1[j];
        }
        *(float4*)(OUT + (size_t)d * DIM + q * 8) = o0;
        *(float4*)(OUT + (size_t)d * DIM + q * 8 + 4) = o1;
    }
}

// ---------------------------------------------------------------- launcher
extern "C" void kernel_launch(void* const* d_in, const int* in_sizes, int n_in,
                              void* d_out, int out_size, void* d_ws, size_t ws_size,
                              hipStream_t stream) {
    const float* X    = (const float*)d_in[0];
    const int*   EIDX = (const int*)d_in[1];
    const float* W    = (const float*)d_in[2];
    const float* ASRC = (const float*)d_in[3];
    const float* ADST = (const float*)d_in[4];
    const float* BIAS = (const float*)d_in[5];
    const float* LNS  = (const float*)d_in[6];
    const float* LNB  = (const float*)d_in[7];
    float* OUT = (float*)d_out;

    char* ws = (char*)d_ws;
    unsigned short* H  = (unsigned short*)(ws);                   // 25,600,000
    unsigned short* Wt = (unsigned short*)(ws + 25600000);        //    131,072
    float* a_srcW      = (float*)(ws + 25731072);                 //  1,600,000
    float* a_dstW      = (float*)(ws + 27331072);                 //  1,600,000
    int*   deg         = (int*)(ws + 28931072);                   //    200,000
    int*   row_start   = (int*)(ws + 29131072);                   //    200,016
    int*   cursor      = (int*)(ws + 29331088);                   //    200,000
    int*   csr_src     = (int*)(ws + 29531088);                   //  3,200,000
    float* wcsr        = (float*)(ws + 32731136);                 // 25,600,000
    int*   bsum        = (int*)(ws + 58331136);                   //        784
    int*   boff        = (int*)(ws + 58331920);                   //        784

    hipMemsetAsync(deg, 0, NN * sizeof(int), stream);

    dim3 blk(256);
    deg_kernel<<<dim3(NE / 256), blk, 0, stream>>>(EIDX, deg);
    scan1_kernel<<<dim3(NB), blk, 0, stream>>>(deg, row_start, bsum);
    scan2_kernel<<<dim3(1), blk, 0, stream>>>(bsum, boff, row_start);
    scan3_kernel<<<dim3(NB), blk, 0, stream>>>(row_start, boff, cursor);
    cvtw_kernel<<<dim3(256), blk, 0, stream>>>(W, Wt);
    gemm_kernel<<<dim3(391), dim3(512), 0, stream>>>(X, Wt, ASRC, ADST, H, a_srcW, a_dstW);
    fill_kernel<<<dim3(NE / 256), blk, 0, stream>>>(EIDX, a_srcW, a_dstW, cursor, csr_src, wcsr);
    agg_kernel<<<dim3((NN + 3) / 4), blk, 0, stream>>>(
        H, row_start, csr_src, wcsr, X, BIAS, LNS, LNB, OUT);
}

// Round 7
// 308.387 us; speedup vs baseline: 1.0915x; 1.0915x over previous
//
#include <hip/hip_runtime.h>
#include <hip/hip_bf16.h>
#include <cstdint>

#define NN 50000
#define NE 800000
#define DIM 256
#define NH 8
#define NB 196          // (NN+255)/256

typedef short v8s __attribute__((ext_vector_type(8)));
typedef float v4f __attribute__((ext_vector_type(4)));
typedef unsigned short u16x8 __attribute__((ext_vector_type(8)));

__device__ __forceinline__ float b2f(unsigned short u) {
    union { float f; uint32_t i; } c; c.i = ((uint32_t)u) << 16; return c.f;
}
__device__ __forceinline__ unsigned short f2b(float f) {
    union { float f; uint32_t i; } c; c.f = f;
    uint32_t lsb = (c.i >> 16) & 1u;
    return (unsigned short)((c.i + 0x7FFFu + lsb) >> 16);
}

// ---------------------------------------------------------- degree histogram
// int64 vs int32 layout probe: odd words of the first 64 entries are int64
// high halves (all zero) or int32 values (never all zero for random data).
__global__ __launch_bounds__(256) void deg_kernel(const int* __restrict__ e,
                                                  int* __restrict__ deg) {
    const int i = blockIdx.x * 256 + threadIdx.x;   // NE = 3125*256 exactly
    const int lane = threadIdx.x & 63;
    int probe = e[2 * lane + 1];
    unsigned long long nz = __ballot(probe != 0);
    bool is64 = (nz == 0ull);
    int d = is64 ? e[2 * (NE + i)] : e[NE + i];
    atomicAdd(&deg[d], 1);
}

// ------------------------------------------------------------- W -> Wt bf16
__global__ __launch_bounds__(256) void cvtw_kernel(const float* __restrict__ W,
                                                   unsigned short* __restrict__ Wt) {
    int idx = blockIdx.x * 256 + threadIdx.x;   // grid 256 -> 65536
    int k = idx >> 8, n = idx & 255;
    Wt[n * DIM + k] = f2b(W[k * DIM + n]);
}

// ---------------------------------------------------------------- GEMM h = x@W
// BM=64 x BN=256 (full width), 256 threads = 4 waves, each wave owns a 64-col
// strip (all waves share the A panel). BK=64. LDS 46KB -> 3 blocks/CU.
// 782 blocks -> ~3 blocks/CU occupancy (vs 1.5 before).
#define LDA3 72
__global__ __launch_bounds__(256) void gemm_kernel(
    const float* __restrict__ X, const unsigned short* __restrict__ Wt,
    unsigned short* __restrict__ H) {
    __shared__ __align__(16) unsigned short As[64 * LDA3];
    __shared__ __align__(16) unsigned short Bs[256 * LDA3];
    const int t = threadIdx.x;
    const int wc = t >> 6, lane = t & 63;
    const int fr = lane & 15, fq = lane >> 4;
    const int m0 = blockIdx.x * 64;

    v4f acc[4][4];
    #pragma unroll
    for (int mi = 0; mi < 4; ++mi)
        #pragma unroll
        for (int j = 0; j < 4; ++j) acc[mi][j] = (v4f){0.f, 0.f, 0.f, 0.f};

    #pragma unroll
    for (int kt = 0; kt < 256; kt += 64) {
        // stage A: 64 rows x 64 f32 -> bf16 (1024 float4, 4/thread)
        #pragma unroll
        for (int it = 0; it < 4; ++it) {
            int v = t + it * 256;
            int row = v >> 4;
            int c4 = (v & 15) << 2;
            int gr = m0 + row;
            float4 val = make_float4(0.f, 0.f, 0.f, 0.f);
            if (gr < NN) val = *(const float4*)(X + (size_t)gr * DIM + kt + c4);
            ushort4 o;
            o.x = f2b(val.x); o.y = f2b(val.y); o.z = f2b(val.z); o.w = f2b(val.w);
            *(ushort4*)(As + row * LDA3 + c4) = o;
        }
        // stage B: 256 rows x 64 shorts (2048 vec8, 8/thread)
        #pragma unroll
        for (int it = 0; it < 8; ++it) {
            int v = t + it * 256;
            int row = v >> 3;
            int kv = (v & 7) << 3;
            u16x8 val = *(const u16x8*)(Wt + (size_t)row * DIM + kt + kv);
            *(u16x8*)(Bs + row * LDA3 + kv) = val;
        }
        __syncthreads();
        #pragma unroll
        for (int ks = 0; ks < 64; ks += 32) {
            v8s a[4];
            #pragma unroll
            for (int mi = 0; mi < 4; ++mi)
                a[mi] = *(const v8s*)(As + (mi * 16 + fr) * LDA3 + ks + fq * 8);
            #pragma unroll
            for (int j = 0; j < 4; ++j) {
                v8s b = *(const v8s*)(Bs + (wc * 64 + j * 16 + fr) * LDA3 + ks + fq * 8);
                #pragma unroll
                for (int mi = 0; mi < 4; ++mi)
                    acc[mi][j] = __builtin_amdgcn_mfma_f32_16x16x32_bf16(a[mi], b, acc[mi][j], 0, 0, 0);
            }
        }
        __syncthreads();
    }
    #pragma unroll
    for (int mi = 0; mi < 4; ++mi)
        #pragma unroll
        for (int j = 0; j < 4; ++j)
            #pragma unroll
            for (int r = 0; r < 4; ++r) {
                int gr = m0 + mi * 16 + fq * 4 + r;
                int gc = wc * 64 + j * 16 + fr;
                if (gr < NN) H[(size_t)gr * DIM + gc] = f2b(acc[mi][j][r]);
            }
}

// ------------------------------------------------- per-node attention logits
__global__ __launch_bounds__(256) void att_kernel(
    const unsigned short* __restrict__ H, const float* __restrict__ ASRC,
    const float* __restrict__ ADST, float* __restrict__ a_src,
    float* __restrict__ a_dst) {
    const int wave = threadIdx.x >> 6, lane = threadIdx.x & 63;
    const int n = blockIdx.x * 4 + wave;
    if (n >= NN) return;
    float4 as4 = *(const float4*)(ASRC + lane * 4);
    float4 ad4 = *(const float4*)(ADST + lane * 4);
    ushort4 hv = *(const ushort4*)(H + (size_t)n * DIM + lane * 4);
    const unsigned short* hvp = (const unsigned short*)&hv;
    float h0 = b2f(hvp[0]), h1 = b2f(hvp[1]), h2 = b2f(hvp[2]), h3 = b2f(hvp[3]);
    float ps = h0 * as4.x + h1 * as4.y + h2 * as4.z + h3 * as4.w;
    float pd = h0 * ad4.x + h1 * ad4.y + h2 * ad4.z + h3 * ad4.w;
    #pragma unroll
    for (int off = 1; off <= 4; off <<= 1) {
        ps += __shfl_xor(ps, off);
        pd += __shfl_xor(pd, off);
    }
    if ((lane & 7) == 0) {
        a_src[n * NH + (lane >> 3)] = ps;
        a_dst[n * NH + (lane >> 3)] = pd;
    }
}

// ------------------------------------------------------------- two-level scan
__global__ __launch_bounds__(256) void scan1_kernel(const int* __restrict__ deg,
                                                    int* __restrict__ row_start,
                                                    int* __restrict__ bsum) {
    const int t = threadIdx.x, b = blockIdx.x;
    const int i = b * 256 + t;
    const int lane = t & 63, wave = t >> 6;
    int v = (i < NN) ? deg[i] : 0;
    int x = v;
    #pragma unroll
    for (int off = 1; off <= 32; off <<= 1) {
        int y = __shfl_up(x, off);
        if (lane >= off) x += y;
    }
    __shared__ int wt[4];
    if (lane == 63) wt[wave] = x;
    __syncthreads();
    int add = 0;
    #pragma unroll
    for (int w2 = 0; w2 < 4; ++w2) if (w2 < wave) add += wt[w2];
    int incl = x + add;
    if (i < NN) row_start[i] = incl - v;
    if (t == 255) bsum[b] = incl;
}

__global__ __launch_bounds__(256) void scan2_kernel(const int* __restrict__ bsum,
                                                    int* __restrict__ boff,
                                                    int* __restrict__ row_start) {
    const int t = threadIdx.x;
    const int lane = t & 63, wave = t >> 6;
    int v = (t < NB) ? bsum[t] : 0;
    int x = v;
    #pragma unroll
    for (int off = 1; off <= 32; off <<= 1) {
        int y = __shfl_up(x, off);
        if (lane >= off) x += y;
    }
    __shared__ int wt[4];
    if (lane == 63) wt[wave] = x;
    __syncthreads();
    int add = 0;
    #pragma unroll
    for (int w2 = 0; w2 < 4; ++w2) if (w2 < wave) add += wt[w2];
    int incl = x + add;
    if (t < NB) boff[t] = incl - v;
    if (t == 255) row_start[NN] = incl;
}

__global__ __launch_bounds__(256) void scan3_kernel(int* __restrict__ row_start,
                                                    const int* __restrict__ boff,
                                                    int* __restrict__ cursor) {
    const int i = blockIdx.x * 256 + threadIdx.x;
    if (i < NN) {
        int r = row_start[i] + boff[blockIdx.x];
        row_start[i] = r;
        cursor[i] = r;
    }
}

// -------------------------------------- CSR fill + per-edge softmax weights
__global__ __launch_bounds__(256) void fill_kernel(
    const int* __restrict__ e, const float* __restrict__ a_src,
    const float* __restrict__ a_dst, int* __restrict__ cursor,
    int* __restrict__ csr_src, float* __restrict__ wcsr) {
    const int i = blockIdx.x * 256 + threadIdx.x;
    const int lane = threadIdx.x & 63;
    int probe = e[2 * lane + 1];
    unsigned long long nz = __ballot(probe != 0);
    bool is64 = (nz == 0ull);
    int s, d;
    if (is64) { s = e[2 * i]; d = e[2 * (NE + i)]; }
    else      { s = e[i];     d = e[NE + i]; }
    int pos = atomicAdd(&cursor[d], 1);
    csr_src[pos] = s;
    float4 as0 = *(const float4*)(a_src + (size_t)s * NH);
    float4 as1 = *(const float4*)(a_src + (size_t)s * NH + 4);
    float4 ad0 = *(const float4*)(a_dst + (size_t)d * NH);
    float4 ad1 = *(const float4*)(a_dst + (size_t)d * NH + 4);
    const float* asp0 = (const float*)&as0; const float* asp1 = (const float*)&as1;
    const float* adp0 = (const float*)&ad0; const float* adp1 = (const float*)&ad1;
    float4 w0, w1;
    float* wp0 = (float*)&w0; float* wp1 = (float*)&w1;
    #pragma unroll
    for (int h = 0; h < 4; ++h) {
        float lg = asp0[h] + adp0[h];
        lg = lg > 0.f ? lg : 0.2f * lg;
        wp0[h] = __expf(lg);
        float lg2 = asp1[h] + adp1[h];
        lg2 = lg2 > 0.f ? lg2 : 0.2f * lg2;
        wp1[h] = __expf(lg2);
    }
    *(float4*)(wcsr + (size_t)pos * NH) = w0;
    *(float4*)(wcsr + (size_t)pos * NH + 4) = w1;
}

// --------------------------------------- fused aggregate+ELU+LayerNorm
// one wave per dst node; 16-edge chunks, slot=lane>>5 takes 8 contiguous
// edges -> 8 independent csr/wcsr loads then 8 independent H-row loads in
// flight (deep MLP). q=lane&31 owns channels q*8..q*8+7.
__global__ __launch_bounds__(256) void agg_kernel(
    const unsigned short* __restrict__ H, const int* __restrict__ row_start,
    const int* __restrict__ csr_src, const float* __restrict__ wcsr,
    const float* __restrict__ X, const float* __restrict__ BIAS,
    const float* __restrict__ LNS, const float* __restrict__ LNB,
    float* __restrict__ OUT) {
    const int wave = threadIdx.x >> 6, lane = threadIdx.x & 63;
    const int d = blockIdx.x * 4 + wave;
    if (d >= NN) return;
    const int base = row_start[d];
    const int degree = row_start[d + 1] - base;
    const int slot = lane >> 5;
    const int q = lane & 31;
    const int headq = q >> 2;

    // hoist epilogue operands
    float4 x0 = *(const float4*)(X + (size_t)d * DIM + q * 8);
    float4 x1 = *(const float4*)(X + (size_t)d * DIM + q * 8 + 4);
    float4 b0 = *(const float4*)(BIAS + q * 8);
    float4 b1 = *(const float4*)(BIAS + q * 8 + 4);
    float4 sc0 = *(const float4*)(LNS + q * 8);
    float4 sc1 = *(const float4*)(LNS + q * 8 + 4);
    float4 lb0 = *(const float4*)(LNB + q * 8);
    float4 lb1 = *(const float4*)(LNB + q * 8 + 4);

    float acc[8];
    #pragma unroll
    for (int j = 0; j < 8; ++j) acc[j] = 0.f;
    float sumw = 0.f;

    for (int c0 = 0; c0 < degree; c0 += 16) {
        const int e0 = c0 + slot * 8;
        const int rem = degree - e0;          // wave-uniform
        const size_t eb = (size_t)base + e0;
        int s[8]; float w[8];
        #pragma unroll
        for (int k = 0; k < 8; ++k) { s[k] = 0; w[k] = 0.f; }
        #pragma unroll
        for (int k = 0; k < 8; ++k)
            if (rem > k) { s[k] = csr_src[eb + k]; w[k] = wcsr[(eb + k) * NH + headq]; }
        u16x8 hv[8];
        #pragma unroll
        for (int k = 0; k < 8; ++k)
            hv[k] = *(const u16x8*)(H + (size_t)s[k] * DIM + q * 8);
        #pragma unroll
        for (int k = 0; k < 8; ++k) {
            sumw += w[k];
            #pragma unroll
            for (int j = 0; j < 8; ++j) acc[j] += w[k] * b2f(hv[k][j]);
        }
    }

    // combine the two slots
    float sum_ex = sumw + __shfl_xor(sumw, 32);
    #pragma unroll
    for (int j = 0; j < 8; ++j) acc[j] += __shfl_xor(acc[j], 32);

    const float inv = 1.0f / (sum_ex + 1e-16f);

    const float* xp0 = (const float*)&x0; const float* xp1 = (const float*)&x1;
    const float* bp0 = (const float*)&b0; const float* bp1 = (const float*)&b1;
    float v[8];
    float s1v = 0.f, s2v = 0.f;
    #pragma unroll
    for (int j = 0; j < 8; ++j) {
        float xv = (j < 4) ? xp0[j] : xp1[j - 4];
        float bv = (j < 4) ? bp0[j] : bp1[j - 4];
        float t = acc[j] * inv + bv + xv;
        t = t > 0.f ? t : expm1f(t);   // ELU
        v[j] = t;
        s1v += t;
        s2v += t * t;
    }
    #pragma unroll
    for (int off = 16; off >= 1; off >>= 1) {
        s1v += __shfl_xor(s1v, off);
        s2v += __shfl_xor(s2v, off);
    }
    const float mean = s1v * (1.0f / 256.0f);
    float var = s2v * (1.0f / 256.0f) - mean * mean;
    var = fmaxf(var, 0.f);
    const float rstd = rsqrtf(var + 1e-5f);

    if (slot == 0) {
        const float* scp0 = (const float*)&sc0; const float* scp1 = (const float*)&sc1;
        const float* lbp0 = (const float*)&lb0; const float* lbp1 = (const float*)&lb1;
        float4 o0, o1;
        float* op0 = (float*)&o0; float* op1 = (float*)&o1;
        #pragma unroll
        for (int j = 0; j < 4; ++j) {
            op0[j] = (v[j] - mean) * rstd * scp0[j] + lbp0[j];
            op1[j] = (v[j + 4] - mean) * rstd * scp1[j] + lbp1[j];
        }
        *(float4*)(OUT + (size_t)d * DIM + q * 8) = o0;
        *(float4*)(OUT + (size_t)d * DIM + q * 8 + 4) = o1;
    }
}

// ---------------------------------------------------------------- launcher
extern "C" void kernel_launch(void* const* d_in, const int* in_sizes, int n_in,
                              void* d_out, int out_size, void* d_ws, size_t ws_size,
                              hipStream_t stream) {
    const float* X    = (const float*)d_in[0];
    const int*   EIDX = (const int*)d_in[1];
    const float* W    = (const float*)d_in[2];
    const float* ASRC = (const float*)d_in[3];
    const float* ADST = (const float*)d_in[4];
    const float* BIAS = (const float*)d_in[5];
    const float* LNS  = (const float*)d_in[6];
    const float* LNB  = (const float*)d_in[7];
    float* OUT = (float*)d_out;

    char* ws = (char*)d_ws;
    unsigned short* H  = (unsigned short*)(ws);                   // 25,600,000
    unsigned short* Wt = (unsigned short*)(ws + 25600000);        //    131,072
    float* a_srcW      = (float*)(ws + 25731072);                 //  1,600,000
    float* a_dstW      = (float*)(ws + 27331072);                 //  1,600,000
    int*   deg         = (int*)(ws + 28931072);                   //    200,000
    int*   row_start   = (int*)(ws + 29131072);                   //    200,016
    int*   cursor      = (int*)(ws + 29331088);                   //    200,000
    int*   csr_src     = (int*)(ws + 29531088);                   //  3,200,000
    float* wcsr        = (float*)(ws + 32731136);                 // 25,600,000
    int*   bsum        = (int*)(ws + 58331136);                   //        784
    int*   boff        = (int*)(ws + 58331920);                   //        784

    hipMemsetAsync(deg, 0, NN * sizeof(int), stream);

    dim3 blk(256);
    deg_kernel<<<dim3(NE / 256), blk, 0, stream>>>(EIDX, deg);
    scan1_kernel<<<dim3(NB), blk, 0, stream>>>(deg, row_start, bsum);
    scan2_kernel<<<dim3(1), blk, 0, stream>>>(bsum, boff, row_start);
    scan3_kernel<<<dim3(NB), blk, 0, stream>>>(row_start, boff, cursor);
    cvtw_kernel<<<dim3(256), blk, 0, stream>>>(W, Wt);
    gemm_kernel<<<dim3(782), blk, 0, stream>>>(X, Wt, H);
    att_kernel<<<dim3((NN + 3) / 4), blk, 0, stream>>>(H, ASRC, ADST, a_srcW, a_dstW);
    fill_kernel<<<dim3(NE / 256), blk, 0, stream>>>(EIDX, a_srcW, a_dstW, cursor, csr_src, wcsr);
    agg_kernel<<<dim3((NN + 3) / 4), blk, 0, stream>>>(
        H, row_start, csr_src, wcsr, X, BIAS, LNS, LNB, OUT);
}